// Round 7
// baseline (258.088 us; speedup 1.0000x reference)
//
#include <hip/hip_runtime.h>
#include <math.h>

#define Bn 16
#define Ln 1444      // 38*38
#define NCn 21
#define Cn 64
#define NBn 23       // ceil(1444/64)
#define KC 1344      // 21*64
#define REPS 8       // measurement amplification (idempotent body)

// ---- Kernel B: classify (LDS-staged) + transpose + per-block class sums ---
__global__ __launch_bounds__(256) void kB(const float* __restrict__ cls_pred,
                                          const float* __restrict__ source,
                                          int* __restrict__ cls_idx,
                                          float* __restrict__ src_out,
                                          float* __restrict__ bs) {
    int b = blockIdx.x / NBn, m = blockIdx.x % NBn;
    int base = m * 64;
    int lane = threadIdx.x & 63, grp = threadIdx.x >> 6;
    __shared__ float sh[9536];
    __shared__ int cls[64];
    float (*tile)[65] = (float(*)[65])sh;   // [64][65]
    float* clsP = sh + 4160;                // 5376 floats, dead after classify
    float* WS   = sh + 4160;                // [4][1344] overlays clsP

    for (int rep = 0; rep < REPS; rep++) {
#pragma unroll
        for (int cc = 0; cc < 16; cc++) {
            int c = grp * 16 + cc;
            float v = 0.f;
            if (base + lane < Ln) v = source[((size_t)b * Cn + c) * Ln + base + lane];
            tile[c][lane] = v;
        }
        {
            const float4* gp = reinterpret_cast<const float4*>(cls_pred + ((size_t)b * Ln + base) * 84);
            int lim4 = (Ln - base) * 21;
#pragma unroll
            for (int it = 0; it < 6; it++) {
                int f4 = threadIdx.x + it * 256;
                if (f4 < 1344) {
                    float4 v = (f4 < lim4) ? gp[f4] : make_float4(0.f, 0.f, 0.f, 0.f);
                    reinterpret_cast<float4*>(clsP)[f4] = v;
                }
            }
        }
        __syncthreads();   // S1

        {
            int p = threadIdx.x >> 2, a = threadIdx.x & 3;
            bool valid = (base + p < Ln);
            const float* q = clsP + p * 84 + a * 21;
            float x[21];
#pragma unroll
            for (int i = 0; i < 21; i++) x[i] = q[i];
            float mx = x[0];
#pragma unroll
            for (int i = 1; i < 21; i++) mx = fmaxf(mx, x[i]);
            float s = 0.f;
#pragma unroll
            for (int i = 0; i < 21; i++) { x[i] = expf(x[i] - mx); s += x[i]; }
            float best = -1.f; int bi = 0;
#pragma unroll
            for (int i = 0; i < 21; i++) {
                float sm = x[i] / s;
                if (sm > best) { best = sm; bi = a * 21 + i; }
            }
#pragma unroll
            for (int d = 1; d <= 2; d <<= 1) {
                float ob = __shfl_xor(best, d);
                int oi = __shfl_xor(bi, d);
                if (ob > best || (ob == best && oi < bi)) { best = ob; bi = oi; }
            }
            if (a == 0) {
                if (valid) { int k = bi % 21; cls[p] = k; cls_idx[b * Ln + base + p] = k; }
                else cls[p] = 255;
            }
        }
        __syncthreads();   // S2

        float cs[21];
#pragma unroll
        for (int k = 0; k < 21; k++) cs[k] = 0.f;
#pragma unroll
        for (int jj = 0; jj < 16; jj++) {
            int j = grp * 16 + jj;
            float v = tile[lane][j];
            if (base + j < Ln) src_out[((size_t)b * Ln + base + j) * Cn + lane] = v;
            int k = cls[j];
#pragma unroll
            for (int kk = 0; kk < 21; kk++) cs[kk] += (kk == k) ? v : 0.f;
        }
#pragma unroll
        for (int kk = 0; kk < 21; kk++) WS[grp * KC + kk * 64 + lane] = cs[kk];
        __syncthreads();   // S3

        for (int i = threadIdx.x; i < KC; i += 256) {
            float v = WS[i] + WS[KC + i] + WS[2 * KC + i] + WS[3 * KC + i];
            bs[((size_t)b * NBn + m) * KC + i] = v;
        }
        __syncthreads();   // rep boundary
    }
}

// ---- Kernel C: batched stream + register running sums ---------------------
__global__ __launch_bounds__(256) void kC(const float* __restrict__ src,
                                          const int* __restrict__ cls_idx,
                                          const float* __restrict__ R,
                                          const float* __restrict__ bs,
                                          float* __restrict__ fused) {
    int b = blockIdx.x / NBn, m = blockIdx.x % NBn;
    int base = m * 64;
    int lane = threadIdx.x & 63, grp = threadIdx.x >> 6;
    __shared__ float PS[KC];
    __shared__ float Tt[KC];
    __shared__ float Ul[KC];
    __shared__ float WS[4][KC];
    __shared__ float Rd[21][22];
    __shared__ float Rl[441];
    __shared__ float Rdg[21];
    __shared__ int cls[64];

    for (int rep = 0; rep < REPS; rep++) {
        float sT[16];
#pragma unroll
        for (int t = 0; t < 16; t++) {
            int i = grp * 16 + t;
            sT[t] = (base + i < Ln) ? src[((size_t)b * Ln + base + i) * Cn + lane] : 0.f;
        }
        if (threadIdx.x < 64) {
            int k = 255;
            if (base + (int)threadIdx.x < Ln) k = cls_idx[b * Ln + base + threadIdx.x];
            cls[threadIdx.x] = k;
        }
        for (int i = threadIdx.x; i < 441; i += 256) {
            float r = R[i];
            Rl[i] = r;
            int aa = i / 21, kk = i % 21;
            Rd[aa][kk] = r - R[kk * 21 + aa];
        }
        if (threadIdx.x < 21) Rdg[threadIdx.x] = R[threadIdx.x * 22];

        for (int g = threadIdx.x; g < KC / 4; g += 256) {
            float rx = 0.f, ry = 0.f, rz = 0.f, rw = 0.f;
            float px = 0.f, py = 0.f, pz = 0.f, pw = 0.f;
#pragma unroll
            for (int mm = 0; mm < NBn; mm++) {
                float4 v = *reinterpret_cast<const float4*>(&bs[((size_t)b * NBn + mm) * KC + g * 4]);
                rx += v.x; ry += v.y; rz += v.z; rw += v.w;
                if (mm < m) { px += v.x; py += v.y; pz += v.z; pw += v.w; }
            }
            PS[g * 4] = px; PS[g * 4 + 1] = py; PS[g * 4 + 2] = pz; PS[g * 4 + 3] = pw;
            Tt[g * 4] = rx; Tt[g * 4 + 1] = ry; Tt[g * 4 + 2] = rz; Tt[g * 4 + 3] = rw;
        }
        __syncthreads();

        for (int p = threadIdx.x; p < KC; p += 256) {
            int aa = p >> 6, c = p & 63;
            float u = 0.f;
#pragma unroll
            for (int k = 0; k < 21; k++) u += Rl[k * 21 + aa] * Tt[k * 64 + c];
            Ul[p] = u;
        }

        float cs[21];
#pragma unroll
        for (int k = 0; k < 21; k++) cs[k] = 0.f;
#pragma unroll
        for (int t = 0; t < 16; t++) {
            int j = grp * 16 + t;
            int k = cls[j];
            float v = sT[t];
#pragma unroll
            for (int kk = 0; kk < 21; kk++) cs[kk] += (kk == k) ? v : 0.f;
        }
#pragma unroll
        for (int kk = 0; kk < 21; kk++) WS[grp][kk * 64 + lane] = cs[kk];
        __syncthreads();

        float ms[21];
#pragma unroll
        for (int k = 0; k < 21; k++) {
            float x = PS[k * 64 + lane];
#pragma unroll
            for (int g = 0; g < 3; g++)
                if (g < grp) x += WS[g][k * 64 + lane];
            ms[k] = x;
        }

        int nvalid = (Ln - base < 64) ? (Ln - base) : 64;
        for (int t = 0; t < 16; t++) {
            int i = grp * 16 + t;
            if (i >= nvalid) break;
            int ci = cls[i];
            float acc = Ul[ci * 64 + lane] + (((ci != 0) ? 1.f : 0.f) - Rdg[ci]) * sT[t];
#pragma unroll
            for (int k = 0; k < 21; k++) acc += Rd[ci][k] * ms[k];
            fused[((size_t)b * Ln + base + i) * Cn + lane] = acc;
            float v = sT[t];
#pragma unroll
            for (int kk = 0; kk < 21; kk++) ms[kk] += (kk == ci) ? v : 0.f;
        }
        __syncthreads();   // rep boundary
    }
}

extern "C" void kernel_launch(void* const* d_in, const int* in_sizes, int n_in,
                              void* d_out, int out_size, void* d_ws, size_t ws_size,
                              hipStream_t stream) {
    const float* cls_pred = (const float*)d_in[0];
    const float* source = (const float*)d_in[1];
    const float* cls_r_prob = (const float*)d_in[2];

    float* fused = (float*)d_out;
    float* src_out = fused + (size_t)Bn * Ln * Cn;

    char* w = (char*)d_ws;
    int* cls_idx = (int*)w;
    size_t off = ((size_t)Bn * Ln * 4 + 1023) & ~(size_t)1023;
    float* bs = (float*)(w + off);

    hipLaunchKernelGGL(kB, dim3(Bn * NBn), dim3(256), 0, stream,
                       cls_pred, source, cls_idx, src_out, bs);
    hipLaunchKernelGGL(kC, dim3(Bn * NBn), dim3(256), 0, stream,
                       src_out, cls_idx, cls_r_prob, bs, fused);
}

// Round 8
// 59.643 us; speedup vs baseline: 4.3272x; 4.3272x over previous
//
#include <hip/hip_runtime.h>
#include <math.h>

#define Bn 16
#define Ln 1444      // 38*38
#define NCn 21
#define Cn 64
#define NBn 23       // 64-position tiles (kB)
#define NQ 46        // 32-position tiles (kC, bs granularity)
#define KC 1344      // 21*64

// ---- Kernel B: classify (LDS-staged) + transpose + half-tile class sums ---
// LDS: [0,4160) tile[64][65]; [4160,9536) clsP (5376 floats) -> overlaid by WS[4][1344]
__global__ __launch_bounds__(256) void kB(const float* __restrict__ cls_pred,
                                          const float* __restrict__ source,
                                          int* __restrict__ cls_idx,
                                          float* __restrict__ src_out,
                                          float* __restrict__ bs) {
    int b = blockIdx.x / NBn, m = blockIdx.x % NBn;
    int base = m * 64;
    int lane = threadIdx.x & 63, grp = threadIdx.x >> 6;
    __shared__ float sh[9536];
    __shared__ int cls[64];
    float (*tile)[65] = (float(*)[65])sh;   // [64][65]
    float* clsP = sh + 4160;                // 5376 floats, dead after classify
    float* WS   = sh + 4160;                // [4][1344] overlays clsP

    // stage source tile (coalesced): tile[c][j] = source[b, c, base+j]
#pragma unroll
    for (int cc = 0; cc < 16; cc++) {
        int c = grp * 16 + cc;
        float v = 0.f;
        if (base + lane < Ln) v = source[((size_t)b * Cn + c) * Ln + base + lane];
        tile[c][lane] = v;
    }
    // stage cls_pred tile (coalesced float4): 64 pos x 84 floats
    {
        const float4* gp = reinterpret_cast<const float4*>(cls_pred + ((size_t)b * Ln + base) * 84);
        int lim4 = (Ln - base) * 21;
#pragma unroll
        for (int it = 0; it < 6; it++) {
            int f4 = threadIdx.x + it * 256;
            if (f4 < 1344) {
                float4 v = (f4 < lim4) ? gp[f4] : make_float4(0.f, 0.f, 0.f, 0.f);
                reinterpret_cast<float4*>(clsP)[f4] = v;
            }
        }
    }
    __syncthreads();   // S1

    // classify from LDS: thread = position p (64) x anchor a (4)
    {
        int p = threadIdx.x >> 2, a = threadIdx.x & 3;
        bool valid = (base + p < Ln);
        const float* q = clsP + p * 84 + a * 21;
        float x[21];
#pragma unroll
        for (int i = 0; i < 21; i++) x[i] = q[i];
        float mx = x[0];
#pragma unroll
        for (int i = 1; i < 21; i++) mx = fmaxf(mx, x[i]);
        float s = 0.f;
#pragma unroll
        for (int i = 0; i < 21; i++) { x[i] = expf(x[i] - mx); s += x[i]; }
        float best = -1.f; int bi = 0;
#pragma unroll
        for (int i = 0; i < 21; i++) {
            float sm = x[i] / s;                     // exact per-element division (matches ref)
            if (sm > best) { best = sm; bi = a * 21 + i; }
        }
#pragma unroll
        for (int d = 1; d <= 2; d <<= 1) {
            float ob = __shfl_xor(best, d);
            int oi = __shfl_xor(bi, d);
            if (ob > best || (ob == best && oi < bi)) { best = ob; bi = oi; }
        }
        if (a == 0) {
            if (valid) { int k = bi % 21; cls[p] = k; cls_idx[b * Ln + base + p] = k; }
            else cls[p] = 255;
        }
    }
    __syncthreads();   // S2: cls ready, clsP dead

    // src write + per-class register sums of own 16 positions
    float cs[21];
#pragma unroll
    for (int k = 0; k < 21; k++) cs[k] = 0.f;
#pragma unroll
    for (int jj = 0; jj < 16; jj++) {
        int j = grp * 16 + jj;
        float v = tile[lane][j];                 // stride-65: conflict-free
        if (base + j < Ln) src_out[((size_t)b * Ln + base + j) * Cn + lane] = v;
        int k = cls[j];                          // wave-uniform broadcast
#pragma unroll
        for (int kk = 0; kk < 21; kk++) cs[kk] += (kk == k) ? v : 0.f;
    }
#pragma unroll
    for (int kk = 0; kk < 21; kk++) WS[grp * KC + kk * 64 + lane] = cs[kk];
    __syncthreads();   // S3: WS ready

    // emit bs at 32-granularity: tile 2m = waves 0+1 (pos 0..31), 2m+1 = waves 2+3
    {
        size_t o0 = ((size_t)b * NQ + 2 * m) * KC;
        for (int i = threadIdx.x; i < KC; i += 256) {
            float h0 = WS[i] + WS[KC + i];
            float h1 = WS[2 * KC + i] + WS[3 * KC + i];
            bs[o0 + i] = h0;
            bs[o0 + KC + i] = h1;
        }
    }
}

// ---- Kernel C: 32-position tiles, Q-table merged combine ------------------
__global__ __launch_bounds__(256, 3) void kC(const float* __restrict__ src,
                                             const int* __restrict__ cls_idx,
                                             const float* __restrict__ R,
                                             const float* __restrict__ bs,
                                             float* __restrict__ fused) {
    int b = blockIdx.x / NQ, q = blockIdx.x % NQ;
    int base = q * 32;
    int lane = threadIdx.x & 63, grp = threadIdx.x >> 6;
    __shared__ float PS[KC];       // prefix over fine tiles < q
    __shared__ float Tt[KC];       // batch totals
    __shared__ float WS[4][KC];    // per-wave (8-position) class sums
    __shared__ float2 Q[441];      // (R[a][k]-R[k][a], R[k][a])
    __shared__ int cls32[32];

    // own 8 positions into registers (coalesced rows)
    float sT[8];
#pragma unroll
    for (int t = 0; t < 8; t++) {
        int i = grp * 8 + t;
        sT[t] = (base + i < Ln) ? src[((size_t)b * Ln + base + i) * Cn + lane] : 0.f;
    }
    if (threadIdx.x < 32) {
        int k = 255;
        if (base + (int)threadIdx.x < Ln) k = cls_idx[b * Ln + base + threadIdx.x];
        cls32[threadIdx.x] = k;
    }
    // build Q
    for (int i = threadIdx.x; i < 441; i += 256) {
        int a = i / 21, k = i % 21;
        float rak = R[a * 21 + k], rka = R[k * 21 + a];
        Q[i] = make_float2(rak - rka, rka);
    }
    // stream bs: 46 fine tiles, float4, fully unrolled independent loads
    for (int g = threadIdx.x; g < KC / 4; g += 256) {
        float rx = 0.f, ry = 0.f, rz = 0.f, rw = 0.f;
        float px = 0.f, py = 0.f, pz = 0.f, pw = 0.f;
#pragma unroll
        for (int mm = 0; mm < NQ; mm++) {
            float4 v = *reinterpret_cast<const float4*>(&bs[((size_t)b * NQ + mm) * KC + g * 4]);
            rx += v.x; ry += v.y; rz += v.z; rw += v.w;
            if (mm < q) { px += v.x; py += v.y; pz += v.z; pw += v.w; }  // uniform branch
        }
        PS[g * 4] = px; PS[g * 4 + 1] = py; PS[g * 4 + 2] = pz; PS[g * 4 + 3] = pw;
        Tt[g * 4] = rx; Tt[g * 4 + 1] = ry; Tt[g * 4 + 2] = rz; Tt[g * 4 + 3] = rw;
    }
    __syncthreads();   // PS/Tt/Q/cls32 ready

    // Tt column once into registers
    float Tc[21];
#pragma unroll
    for (int k = 0; k < 21; k++) Tc[k] = Tt[k * 64 + lane];

    // own-chunk class sums (8 positions) -> WS
    {
        float cs[21];
#pragma unroll
        for (int k = 0; k < 21; k++) cs[k] = 0.f;
#pragma unroll
        for (int t = 0; t < 8; t++) {
            int j = grp * 8 + t;
            int k = cls32[j];                    // wave-uniform
#pragma unroll
            for (int kk = 0; kk < 21; kk++) cs[kk] += (kk == k) ? sT[t] : 0.f;
        }
#pragma unroll
        for (int kk = 0; kk < 21; kk++) WS[grp][kk * 64 + lane] = cs[kk];
    }
    __syncthreads();   // WS ready

    // running sums: PS + earlier waves' chunks
    float ms[21];
#pragma unroll
    for (int k = 0; k < 21; k++) {
        float x = PS[k * 64 + lane];
        if (grp > 0) x += WS[0][k * 64 + lane];
        if (grp > 1) x += WS[1][k * 64 + lane];
        if (grp > 2) x += WS[2][k * 64 + lane];
        ms[k] = x;
    }

    // serial over own 8 positions — 21 ds_read_b64 broadcast + 42 FMA each
    int nvalid = (Ln - base < 32) ? (Ln - base) : 32;
    for (int t = 0; t < 8; t++) {
        int i = grp * 8 + t;
        if (i >= nvalid) break;
        int ci = cls32[i];                       // wave-uniform
        float sv = sT[t];
        float rdiag = Q[ci * 21 + ci].y;
        float acc = (((ci != 0) ? 1.f : 0.f) - rdiag) * sv;
#pragma unroll
        for (int k = 0; k < 21; k++) {
            float2 w = Q[ci * 21 + k];           // broadcast b64
            acc += w.x * ms[k] + w.y * Tc[k];
        }
        fused[((size_t)b * Ln + base + i) * Cn + lane] = acc;
#pragma unroll
        for (int kk = 0; kk < 21; kk++) ms[kk] += (kk == ci) ? sv : 0.f;
    }
}

extern "C" void kernel_launch(void* const* d_in, const int* in_sizes, int n_in,
                              void* d_out, int out_size, void* d_ws, size_t ws_size,
                              hipStream_t stream) {
    const float* cls_pred = (const float*)d_in[0];
    const float* source = (const float*)d_in[1];
    const float* cls_r_prob = (const float*)d_in[2];

    float* fused = (float*)d_out;
    float* src_out = fused + (size_t)Bn * Ln * Cn;

    char* w = (char*)d_ws;
    int* cls_idx = (int*)w;                                    // 92416 B
    size_t off = ((size_t)Bn * Ln * 4 + 1023) & ~(size_t)1023;
    float* bs = (float*)(w + off);                             // 16*46*1344*4 = 3.96 MB

    hipLaunchKernelGGL(kB, dim3(Bn * NBn), dim3(256), 0, stream,
                       cls_pred, source, cls_idx, src_out, bs);
    hipLaunchKernelGGL(kC, dim3(Bn * NQ), dim3(256), 0, stream,
                       src_out, cls_idx, cls_r_prob, bs, fused);
}

// Round 9
// 40.452 us; speedup vs baseline: 6.3801x; 1.4744x over previous
//
#include <hip/hip_runtime.h>
#include <math.h>

#define Bn 16
#define Ln 1444      // 38*38
#define NCn 21
#define Cn 64
#define NBn 23       // 64-position tiles
#define KC 1344      // 21*64

// ---- Kernel B: classify (LDS-staged) + transpose + per-block class sums ---
// (R6 version, measured ~7-8 us)
__global__ __launch_bounds__(256) void kB(const float* __restrict__ cls_pred,
                                          const float* __restrict__ source,
                                          int* __restrict__ cls_idx,
                                          float* __restrict__ src_out,
                                          float* __restrict__ bs) {
    int b = blockIdx.x / NBn, m = blockIdx.x % NBn;
    int base = m * 64;
    int lane = threadIdx.x & 63, grp = threadIdx.x >> 6;
    __shared__ float sh[9536];
    __shared__ int cls[64];
    float (*tile)[65] = (float(*)[65])sh;   // [64][65]
    float* clsP = sh + 4160;                // 5376 floats, dead after classify
    float* WS   = sh + 4160;                // [4][1344] overlays clsP

    // stage source tile (coalesced): tile[c][j] = source[b, c, base+j]
#pragma unroll
    for (int cc = 0; cc < 16; cc++) {
        int c = grp * 16 + cc;
        float v = 0.f;
        if (base + lane < Ln) v = source[((size_t)b * Cn + c) * Ln + base + lane];
        tile[c][lane] = v;
    }
    // stage cls_pred tile (coalesced float4): 64 pos x 84 floats
    {
        const float4* gp = reinterpret_cast<const float4*>(cls_pred + ((size_t)b * Ln + base) * 84);
        int lim4 = (Ln - base) * 21;
#pragma unroll
        for (int it = 0; it < 6; it++) {
            int f4 = threadIdx.x + it * 256;
            if (f4 < 1344) {
                float4 v = (f4 < lim4) ? gp[f4] : make_float4(0.f, 0.f, 0.f, 0.f);
                reinterpret_cast<float4*>(clsP)[f4] = v;
            }
        }
    }
    __syncthreads();   // S1

    // classify from LDS: thread = position p (64) x anchor a (4)
    {
        int p = threadIdx.x >> 2, a = threadIdx.x & 3;
        bool valid = (base + p < Ln);
        const float* q = clsP + p * 84 + a * 21;
        float x[21];
#pragma unroll
        for (int i = 0; i < 21; i++) x[i] = q[i];
        float mx = x[0];
#pragma unroll
        for (int i = 1; i < 21; i++) mx = fmaxf(mx, x[i]);
        float s = 0.f;
#pragma unroll
        for (int i = 0; i < 21; i++) { x[i] = expf(x[i] - mx); s += x[i]; }
        float best = -1.f; int bi = 0;
#pragma unroll
        for (int i = 0; i < 21; i++) {
            float sm = x[i] / s;                     // exact per-element division (matches ref)
            if (sm > best) { best = sm; bi = a * 21 + i; }
        }
#pragma unroll
        for (int d = 1; d <= 2; d <<= 1) {
            float ob = __shfl_xor(best, d);
            int oi = __shfl_xor(bi, d);
            if (ob > best || (ob == best && oi < bi)) { best = ob; bi = oi; }
        }
        if (a == 0) {
            if (valid) { int k = bi % 21; cls[p] = k; cls_idx[b * Ln + base + p] = k; }
            else cls[p] = 255;
        }
    }
    __syncthreads();   // S2: cls ready, clsP dead

    // src write + per-class register sums of own 16 positions
    float cs[21];
#pragma unroll
    for (int k = 0; k < 21; k++) cs[k] = 0.f;
#pragma unroll
    for (int jj = 0; jj < 16; jj++) {
        int j = grp * 16 + jj;
        float v = tile[lane][j];                 // stride-65: conflict-free
        if (base + j < Ln) src_out[((size_t)b * Ln + base + j) * Cn + lane] = v;
        int k = cls[j];                          // wave-uniform broadcast
#pragma unroll
        for (int kk = 0; kk < 21; kk++) cs[kk] += (kk == k) ? v : 0.f;
    }
#pragma unroll
    for (int kk = 0; kk < 21; kk++) WS[grp * KC + kk * 64 + lane] = cs[kk];
    __syncthreads();   // S3: WS ready

    for (int i = threadIdx.x; i < KC; i += 256) {
        float v = WS[i] + WS[KC + i] + WS[2 * KC + i] + WS[3 * KC + i];
        bs[((size_t)b * NBn + m) * KC + i] = v;
    }
}

// ---- Kernel C: 8 waves/block, 64-pos tiles, Q-table merged combine --------
// LDS: PS+Tt+WS[8] = 10*1344*4 = 53.8 KB, Q 3.5 KB, cls 256 B  (~57.8 KB)
__global__ __launch_bounds__(512, 2) void kC(const float* __restrict__ src,
                                             const int* __restrict__ cls_idx,
                                             const float* __restrict__ R,
                                             const float* __restrict__ bs,
                                             float* __restrict__ fused) {
    int b = blockIdx.x / NBn, m = blockIdx.x % NBn;
    int base = m * 64;
    int lane = threadIdx.x & 63, grp = threadIdx.x >> 6;   // 8 waves, 8 pos each
    __shared__ float PS[KC];       // prefix over tiles < m
    __shared__ float Tt[KC];       // batch totals
    __shared__ float WS[8][KC];    // per-wave (8-position) class sums
    __shared__ float2 Q[441];      // (R[a][k]-R[k][a], R[k][a])
    __shared__ int cls[64];

    // own 8 positions into registers (coalesced rows)
    float sT[8];
#pragma unroll
    for (int t = 0; t < 8; t++) {
        int i = grp * 8 + t;
        sT[t] = (base + i < Ln) ? src[((size_t)b * Ln + base + i) * Cn + lane] : 0.f;
    }
    if (threadIdx.x < 64) {
        int k = 255;
        if (base + (int)threadIdx.x < Ln) k = cls_idx[b * Ln + base + threadIdx.x];
        cls[threadIdx.x] = k;
    }
    if (threadIdx.x < 441) {
        int a = threadIdx.x / 21, k = threadIdx.x % 21;
        float rak = R[a * 21 + k], rka = R[k * 21 + a];
        Q[threadIdx.x] = make_float2(rak - rka, rka);
    }
    // stream bs: threads 0..335 each own one float4 group, 23 batched loads
    if (threadIdx.x < KC / 4) {
        int g = threadIdx.x;
        float rx = 0.f, ry = 0.f, rz = 0.f, rw = 0.f;
        float px = 0.f, py = 0.f, pz = 0.f, pw = 0.f;
#pragma unroll
        for (int mm = 0; mm < NBn; mm++) {
            float4 v = *reinterpret_cast<const float4*>(&bs[((size_t)b * NBn + mm) * KC + g * 4]);
            rx += v.x; ry += v.y; rz += v.z; rw += v.w;
            if (mm < m) { px += v.x; py += v.y; pz += v.z; pw += v.w; }  // uniform branch
        }
        PS[g * 4] = px; PS[g * 4 + 1] = py; PS[g * 4 + 2] = pz; PS[g * 4 + 3] = pw;
        Tt[g * 4] = rx; Tt[g * 4 + 1] = ry; Tt[g * 4 + 2] = rz; Tt[g * 4 + 3] = rw;
    }
    __syncthreads();   // S1: PS/Tt/Q/cls ready

    // own-chunk (8 positions) class sums -> WS
    {
        float cs[21];
#pragma unroll
        for (int k = 0; k < 21; k++) cs[k] = 0.f;
#pragma unroll
        for (int t = 0; t < 8; t++) {
            int j = grp * 8 + t;
            int k = cls[j];                      // wave-uniform broadcast
#pragma unroll
            for (int kk = 0; kk < 21; kk++) cs[kk] += (kk == k) ? sT[t] : 0.f;
        }
#pragma unroll
        for (int kk = 0; kk < 21; kk++) WS[grp][kk * 64 + lane] = cs[kk];
    }
    __syncthreads();   // S2: WS ready

    // Tt column into registers
    float Tc[21];
#pragma unroll
    for (int k = 0; k < 21; k++) Tc[k] = Tt[k * 64 + lane];

    // running sums: PS + earlier waves' chunks
    float ms[21];
#pragma unroll
    for (int k = 0; k < 21; k++) {
        float x = PS[k * 64 + lane];
#pragma unroll
        for (int g = 0; g < 7; g++)
            if (g < grp) x += WS[g][k * 64 + lane];
        ms[k] = x;
    }

    // serial over own 8 positions
    int nvalid = (Ln - base < 64) ? (Ln - base) : 64;
    for (int t = 0; t < 8; t++) {
        int i = grp * 8 + t;
        if (i >= nvalid) break;
        int ci = cls[i];                         // wave-uniform
        float sv = sT[t];
        float rdiag = Q[ci * 21 + ci].y;
        float accA = (((ci != 0) ? 1.f : 0.f) - rdiag) * sv;   // split accumulators
        float accB = 0.f;
#pragma unroll
        for (int k = 0; k < 21; k++) {
            float2 w = Q[ci * 21 + k];           // broadcast ds_read_b64
            accA += w.x * ms[k];
            accB += w.y * Tc[k];
        }
        fused[((size_t)b * Ln + base + i) * Cn + lane] = accA + accB;
#pragma unroll
        for (int kk = 0; kk < 21; kk++) ms[kk] += (kk == ci) ? sv : 0.f;
    }
}

extern "C" void kernel_launch(void* const* d_in, const int* in_sizes, int n_in,
                              void* d_out, int out_size, void* d_ws, size_t ws_size,
                              hipStream_t stream) {
    const float* cls_pred = (const float*)d_in[0];
    const float* source = (const float*)d_in[1];
    const float* cls_r_prob = (const float*)d_in[2];

    float* fused = (float*)d_out;
    float* src_out = fused + (size_t)Bn * Ln * Cn;

    char* w = (char*)d_ws;
    int* cls_idx = (int*)w;                                    // 92416 B
    size_t off = ((size_t)Bn * Ln * 4 + 1023) & ~(size_t)1023;
    float* bs = (float*)(w + off);                             // 16*23*1344*4 = 1.98 MB

    hipLaunchKernelGGL(kB, dim3(Bn * NBn), dim3(256), 0, stream,
                       cls_pred, source, cls_idx, src_out, bs);
    hipLaunchKernelGGL(kC, dim3(Bn * NBn), dim3(512), 0, stream,
                       src_out, cls_idx, cls_r_prob, bs, fused);
}